// Round 1
// baseline (421.418 us; speedup 1.0000x reference)
//
#include <hip/hip_runtime.h>
#include <math.h>

// Problem constants (fixed by the reference):
#define W_    1024              // layer width
#define NL_   8                 // layers (7 matvecs)
#define NTOT_ (W_ * NL_)        // 8192
#define RS_   (NTOT_ + 1)       // params row stride = 8193 floats (bias col 8192)
#define NBLK  256               // 1 block/CU

typedef unsigned long long u64;

// Relaxed agent-scope 8B atomics: single global_load/store_dwordx2 with
// sc0+sc1 (bypass L1 + non-coherent L2, performed at MALL coherence point).
__device__ __forceinline__ u64 ld64(const u64* p) {
    return __hip_atomic_load(p, __ATOMIC_RELAXED, __HIP_MEMORY_SCOPE_AGENT);
}
__device__ __forceinline__ void st64(u64* p, u64 v) {
    __hip_atomic_store(p, v, __ATOMIC_RELAXED, __HIP_MEMORY_SCOPE_AGENT);
}
__device__ __forceinline__ u64 pack(int tag, float v) {
    return ((u64)(unsigned)tag << 32) | (u64)__float_as_uint(v);
}

// Persistent-dataflow kernel, 256 blocks x 256 threads, 1 block/CU.
// PLAIN launch: 1024 waves vs 8192-wave capacity -> every block resident
// immediately, so the spin-wait dataflow cannot deadlock.
//
// v2 changes vs the 411 us version:
//  * ALL 7 layers' weight rows preloaded into registers up front (112 VGPR;
//    fine at 1 wave/SIMD). The per-layer poll no longer vmcnt-drains a fresh
//    16-load HBM burst each layer — the whole 29 MB weight stream is issued
//    once and overlaps the layer-1 compute + layer-2 wait. Layers 3..7 are
//    then pure publish->poll latency.
//  * Per-WAVE register dataflow: each lane polls exactly the 16 packed
//    activations it consumes (cur + lane + 64*i) and FMAs them from
//    registers. No LDS staging, no __syncthreads at all (also removes the
//    latent intra-block h[] overwrite race of the block-staged version).
//    Wave-level transitive barrier still makes ping-pong reuse race-free:
//    a tag-(l+2) publish requires seeing ALL tag-(l+1) values, which
//    requires every wave to have finished reading all tag-l values.
//
// ws's 0xAA harness pre-poison (tag 0xAAAAAAAA) never equals a valid layer
// tag 1..6, so no memset is needed on our side.
__global__ __launch_bounds__(256, 1)
void mlp_fused(const float* __restrict__ x, const float* __restrict__ params,
               float* __restrict__ out, float* __restrict__ ws) {
    const int tid  = threadIdx.x;
    const int lane = tid & 63;
    const int wave = tid >> 6;                 // 0..3
    const int row  = blockIdx.x * 4 + wave;    // 0..1023

    u64* bufs[2] = { (u64*)ws, (u64*)ws + W_ };   // ping-pong packed activations

    // ---- one-shot preload ------------------------------------------------
    // Layer-1 input fragment: lane i covers cols i, i+64, ..., i+960
    // (issued FIRST so the layer-1 dot doesn't wait on the weight stream).
    float vreg[16];
#pragma unroll
    for (int i = 0; i < 16; ++i) vreg[i] = x[lane + 64 * i];

    // Biases for layers 1..7 (wave-uniform -> scalar loads, lgkmcnt domain,
    // no interference with the vmcnt-counted polls).
    float bias[NL_ - 1];
#pragma unroll
    for (int l = 1; l < NL_; ++l)
        bias[l - 1] = params[(size_t)(l * W_ + row) * RS_ + NTOT_];

    // ALL weight rows for this wave's row of every layer: 7 x 16 segments,
    // each segment a coalesced 256 B wave-load. 112 VGPRs.
    float wreg[NL_ - 1][16];
#pragma unroll
    for (int l = 1; l < NL_; ++l) {
        const float* wrow = params + (size_t)(l * W_ + row) * RS_
                                   + (size_t)(l - 1) * W_ + lane;
#pragma unroll
        for (int i = 0; i < 16; ++i) wreg[l - 1][i] = wrow[64 * i];
    }

    // ---- layer chain: dot -> reduce -> publish -> poll next --------------
#pragma unroll
    for (int l = 1; l < NL_; ++l) {
        float acc = 0.f;
#pragma unroll
        for (int i = 0; i < 16; ++i)
            acc += wreg[l - 1][i] * vreg[i];
#pragma unroll
        for (int off = 32; off; off >>= 1)
            acc += __shfl_down(acc, off);

        if (l == NL_ - 1) {
            if (lane == 0) out[row] = acc + bias[l - 1];   // identity output
        } else {
            if (lane == 0) {
                float pre = acc + bias[l - 1];
                float v = pre / (1.f + __expf(-pre));       // silu
                st64(bufs[(l - 1) & 1] + row, pack(l, v));  // publish tag+data
            }
            // Dataflow wait: poll the 16 tag-l values THIS lane consumes.
            // (The first round's vmcnt wait also flushes our own publish and
            // absorbs any still-draining weight loads off the critical path.)
            const u64* cur = bufs[(l - 1) & 1];
            const unsigned want = (unsigned)l;
            u64 u[16];                      // fully unrolled -> registers
            for (;;) {
#pragma unroll
                for (int i = 0; i < 16; ++i) u[i] = ld64(cur + lane + 64 * i);
                bool ok = true;
#pragma unroll
                for (int i = 0; i < 16; ++i)
                    ok &= ((unsigned)(u[i] >> 32) == want);
                if (ok) break;              // per-lane exit; wave leaves when
            }                               // all lanes have their 16 values
#pragma unroll
            for (int i = 0; i < 16; ++i)
                vreg[i] = __uint_as_float((unsigned)u[i]);
        }
    }
}

extern "C" void kernel_launch(void* const* d_in, const int* in_sizes, int n_in,
                              void* d_out, int out_size, void* d_ws, size_t ws_size,
                              hipStream_t stream) {
    const float* x      = (const float*)d_in[0];
    const float* params = (const float*)d_in[1];
    // d_in[2] = adj (bool): fixed layered-DAG structure, baked into indexing.
    float* out = (float*)d_out;
    float* ws  = (float*)d_ws;   // 16 KB used: 2 x 1024 packed u64 activations

    hipLaunchKernelGGL(mlp_fused, dim3(NBLK), dim3(256), 0, stream,
                       x, params, out, ws);
}

// Round 2
// 419.048 us; speedup vs baseline: 1.0057x; 1.0057x over previous
//
#include <hip/hip_runtime.h>
#include <math.h>

// Problem constants (fixed by the reference):
#define W_    1024              // layer width
#define NL_   8                 // layers (7 matvecs)
#define NTOT_ (W_ * NL_)        // 8192
#define RS_   (NTOT_ + 1)       // params row stride = 8193 floats (bias col 8192)
#define NBLK  256               // 1 block/CU

typedef unsigned long long u64;

// Relaxed agent-scope 8B atomics: single global_load/store_dwordx2 with
// sc0+sc1 (bypass L1 + non-coherent L2, performed at MALL coherence point).
__device__ __forceinline__ u64 ld64(const u64* p) {
    return __hip_atomic_load(p, __ATOMIC_RELAXED, __HIP_MEMORY_SCOPE_AGENT);
}
__device__ __forceinline__ void st64(u64* p, u64 v) {
    __hip_atomic_store(p, v, __ATOMIC_RELAXED, __HIP_MEMORY_SCOPE_AGENT);
}
__device__ __forceinline__ u64 pack(int tag, float v) {
    return ((u64)(unsigned)tag << 32) | (u64)__float_as_uint(v);
}

// Persistent-dataflow kernel, 256 blocks x 256 threads, 1 block/CU.
// PLAIN launch: 1024 waves vs 8192-wave capacity -> every block resident
// immediately, so the spin-wait dataflow cannot deadlock.
//
// v3 = v1's block-level poll + LDS sharing (v2's per-wave polling cost
// +10.7 us of MALL poll congestion — reverted), plus:
//  * FULL up-front weight preload (v2's win, kept): all 7x16 segment loads
//    issued once at t=0 (112 VGPR; fine at 1 wave/SIMD). v1's depth-1
//    prefetch re-serialized a 16-load HBM burst into EACH layer's poll
//    vmcnt drain; now the 29 MB stream drains under the first handoff.
//  * Ping-pong LDS h[2][1024]: tag-l values -> h[l&1], iteration-l dot
//    reads h[(l-1)&1]. The single post-write barrier now provably orders
//    every write against prior readers (the next write to the same half is
//    two iterations later, with an intervening barrier) — fixes v1's
//    latent write-after-read race without a second barrier.
//  * Layer-1 input read straight to registers (4 KB, L2-hot) — drops the
//    initial LDS stage + barrier from the startup chain.
//
// Inter-layer handoff is pure dataflow: packed (layer_tag, value) 8B
// atomics; consumers poll the 4 slots they own and share via LDS. ws's
// 0xAA pre-poison (tag 0xAAAAAAAA) never equals a valid tag 1..6, so no
// memset is needed. Global ping-pong reuse (tag l+2 overwrites tag l's
// buffer) is race-free: every block's __syncthreads (which drains the poll
// loads) precedes its l+1 publishes, so any l+2 publish happens-after
// every block finished reading tag l.
__global__ __launch_bounds__(256, 1)
void mlp_fused(const float* __restrict__ x, const float* __restrict__ params,
               float* __restrict__ out, float* __restrict__ ws) {
    __shared__ float h[2][W_];
    const int tid  = threadIdx.x;
    const int lane = tid & 63;
    const int wave = tid >> 6;                 // 0..3
    const int row  = blockIdx.x * 4 + wave;    // 0..1023

    u64* bufs[2] = { (u64*)ws, (u64*)ws + W_ };   // ping-pong packed activations

    // ---- one-shot preload ------------------------------------------------
    // Layer-1 input fragment, straight to registers: lane i covers cols
    // i, i+64, ..., i+960. Issued FIRST so layer 1 never waits on weights.
    float xreg[16];
#pragma unroll
    for (int i = 0; i < 16; ++i) xreg[i] = x[lane + 64 * i];

    // Biases for layers 1..7.
    float bias[NL_ - 1];
#pragma unroll
    for (int l = 1; l < NL_; ++l)
        bias[l - 1] = params[(size_t)(l * W_ + row) * RS_ + NTOT_];

    // ALL weight rows for this wave's row of every layer: 7 x 16 segments,
    // each a coalesced 256 B wave-load. 112 VGPRs.
    float wreg[NL_ - 1][16];
#pragma unroll
    for (int l = 1; l < NL_; ++l) {
        const float* wrow = params + (size_t)(l * W_ + row) * RS_
                                   + (size_t)(l - 1) * W_ + lane;
#pragma unroll
        for (int i = 0; i < 16; ++i) wreg[l - 1][i] = wrow[64 * i];
    }

    // ---- layer chain: dot -> reduce -> publish -> poll -> share ----------
#pragma unroll
    for (int l = 1; l < NL_; ++l) {
        // dot: registered weights x (regs for l=1, LDS stride-64 for l>1;
        // 2-way LDS alias is free)
        float acc = 0.f;
        if (l == 1) {
#pragma unroll
            for (int i = 0; i < 16; ++i)
                acc += wreg[0][i] * xreg[i];
        } else {
            const float* hr = h[(l - 1) & 1];
#pragma unroll
            for (int i = 0; i < 16; ++i)
                acc += wreg[l - 1][i] * hr[lane + 64 * i];
        }
#pragma unroll
        for (int off = 32; off; off >>= 1)
            acc += __shfl_down(acc, off);

        if (l == NL_ - 1) {
            if (lane == 0) out[row] = acc + bias[l - 1];      // identity
        } else {
            if (lane == 0) {
                float pre = acc + bias[l - 1];
                float v = pre / (1.f + __expf(-pre));         // silu
                st64(bufs[(l - 1) & 1] + row, pack(l, v));    // publish tag+data
            }
            // Dataflow wait: poll MY 4 packed tag-l slots (4 loads in
            // flight per round; first round's vmcnt wait also absorbs any
            // still-draining weight loads off the critical path).
            const u64* cur = bufs[(l - 1) & 1];
            const u64 want = (u64)(unsigned)l;
            u64 u0, u1, u2, u3;
            do {
                u0 = ld64(cur + tid);
                u1 = ld64(cur + tid + 256);
                u2 = ld64(cur + tid + 512);
                u3 = ld64(cur + tid + 768);
            } while (((u0 >> 32) != want) | ((u1 >> 32) != want) |
                     ((u2 >> 32) != want) | ((u3 >> 32) != want));
            float* hw = h[l & 1];
            hw[tid]       = __uint_as_float((unsigned)u0);
            hw[tid + 256] = __uint_as_float((unsigned)u1);
            hw[tid + 512] = __uint_as_float((unsigned)u2);
            hw[tid + 768] = __uint_as_float((unsigned)u3);
            __syncthreads();   // drains poll loads; orders this write against
                               // all readers of this LDS half (2 iters apart)
        }
    }
}

extern "C" void kernel_launch(void* const* d_in, const int* in_sizes, int n_in,
                              void* d_out, int out_size, void* d_ws, size_t ws_size,
                              hipStream_t stream) {
    const float* x      = (const float*)d_in[0];
    const float* params = (const float*)d_in[1];
    // d_in[2] = adj (bool): fixed layered-DAG structure, baked into indexing.
    float* out = (float*)d_out;
    float* ws  = (float*)d_ws;   // 16 KB used: 2 x 1024 packed u64 activations

    hipLaunchKernelGGL(mlp_fused, dim3(NBLK), dim3(256), 0, stream,
                       x, params, out, ws);
}

// Round 3
// 411.112 us; speedup vs baseline: 1.0251x; 1.0193x over previous
//
#include <hip/hip_runtime.h>
#include <math.h>

// Problem constants (fixed by the reference):
#define W_    1024              // layer width
#define NL_   8                 // layers (7 matvecs)
#define NTOT_ (W_ * NL_)        // 8192
#define RS_   (NTOT_ + 1)       // params row stride = 8193 floats (bias col 8192)
#define NBLK  256               // 1 block/CU

typedef unsigned long long u64;

// Relaxed agent-scope 8B atomics: single global_load/store_dwordx2 with
// sc0+sc1 (bypass L1 + non-coherent L2, performed at MALL coherence point).
__device__ __forceinline__ u64 ld64(const u64* p) {
    return __hip_atomic_load(p, __ATOMIC_RELAXED, __HIP_MEMORY_SCOPE_AGENT);
}
__device__ __forceinline__ void st64(u64* p, u64 v) {
    __hip_atomic_store(p, v, __ATOMIC_RELAXED, __HIP_MEMORY_SCOPE_AGENT);
}
__device__ __forceinline__ u64 pack(int tag, float v) {
    return ((u64)(unsigned)tag << 32) | (u64)__float_as_uint(v);
}

// Persistent-dataflow kernel, 256 blocks x 256 threads, 1 block/CU.
// PLAIN launch: 1024 waves vs 8192-wave capacity -> every block resident
// immediately, so the spin-wait dataflow cannot deadlock.
//
// v4 = the 410.7 us v1 schedule, restored after two instructive regressions:
//  * v2 (-> 421.4): per-wave register polling. 4x poll traffic at the MALL
//    + 16-deep vmcnt waits stretched every handoff. Reverted.
//  * v3 (-> 419.0): FULL up-front weight preload. vmcnt is a FIFO: the
//    first poll's tag-check then waits behind the whole 29 MB weight
//    stream (256 blocks' worth, queue-saturated latency) -> a serial
//    ~5-8 us prologue on the dependency chain. Reverted to depth-1
//    rolling prefetch: only 16 loads (4 MB aggregate, ~0.65 us) ever sit
//    ahead of a poll, hiding fully under the ~1 us handoff.
// Kept from v3 (both free or better):
//  * Ping-pong LDS h[2][1024] (insurance; single-buffer was provably safe
//    via the detect->publish->read happens-before chain, this makes it
//    obvious).
//  * Layer-1 input straight to registers (drops one LDS stage + barrier
//    from the startup chain; x is 4 KB, L2-hot, redundancy free).
//
// Inter-layer handoff is pure dataflow: packed (layer_tag, value) 8B
// atomics; consumers poll the 4 slots they own and share via LDS. ws's
// 0xAA pre-poison (tag 0xAAAAAAAA) never equals a valid tag 1..6, so no
// memset is needed. Global ping-pong reuse (tag l+2 overwrites tag l's
// buffer) is race-free: a successful tag-(l+1) detect transitively proves
// every wave of every block finished reading tag l.
__global__ __launch_bounds__(256, 1)
void mlp_fused(const float* __restrict__ x, const float* __restrict__ params,
               float* __restrict__ out, float* __restrict__ ws) {
    __shared__ float h[2][W_];
    const int tid  = threadIdx.x;
    const int lane = tid & 63;
    const int wave = tid >> 6;                 // 0..3
    const int row  = blockIdx.x * 4 + wave;    // 0..1023

    u64* bufs[2] = { (u64*)ws, (u64*)ws + W_ };   // ping-pong packed activations

    // Layer-1 input fragment, straight to registers: lane i covers cols
    // i, i+64, ..., i+960 (issued first; layer 1 never waits on weights).
    float xreg[16];
#pragma unroll
    for (int i = 0; i < 16; ++i) xreg[i] = x[lane + 64 * i];

    // Biases for layers 1..7 (wave-uniform loads; complete whenever).
    float bias[NL_ - 1];
#pragma unroll
    for (int l = 1; l < NL_; ++l)
        bias[l - 1] = params[(size_t)(l * W_ + row) * RS_ + NTOT_];

    // Double-buffered weight rows: wreg[(l-1)&1] holds layer l's 16 segments.
    // lane i covers cols i, i+64, ..., i+960 (coalesced 256 B/wave/load).
    float wreg[2][16];
    {
        const float* wrow = params + (size_t)(1 * W_ + row) * RS_ + lane;
#pragma unroll
        for (int i = 0; i < 16; ++i) wreg[0][i] = wrow[64 * i];
    }

    // ---- layer chain: prefetch -> poll -> dot -> publish ------------------
#pragma unroll
    for (int l = 1; l < NL_; ++l) {
        // Rolling depth-1 prefetch, issued BEFORE this layer's poll: the 16
        // loads for layer l+1 drain during the handoff wait (the first poll
        // round's vmcnt wait absorbs them off the critical path).
        if (l < NL_ - 1) {
            const float* wrow = params + (size_t)((l + 1) * W_ + row) * RS_
                                       + (size_t)l * W_ + lane;
#pragma unroll
            for (int i = 0; i < 16; ++i) wreg[l & 1][i] = wrow[64 * i];
        }

        if (l > 1) {
            // Dataflow wait: poll MY 4 packed tag-(l-1) slots (4 loads in
            // flight per round).
            const u64* cur = bufs[l & 1];       // tag l-1 lives in buf[(l-2)&1] == buf[l&1]
            const u64 want = (u64)(unsigned)(l - 1);
            u64 u0, u1, u2, u3;
            do {
                u0 = ld64(cur + tid);
                u1 = ld64(cur + tid + 256);
                u2 = ld64(cur + tid + 512);
                u3 = ld64(cur + tid + 768);
            } while (((u0 >> 32) != want) | ((u1 >> 32) != want) |
                     ((u2 >> 32) != want) | ((u3 >> 32) != want));
            float* hw = h[(l - 1) & 1];
            hw[tid]       = __uint_as_float((unsigned)u0);
            hw[tid + 256] = __uint_as_float((unsigned)u1);
            hw[tid + 512] = __uint_as_float((unsigned)u2);
            hw[tid + 768] = __uint_as_float((unsigned)u3);
            __syncthreads();
        }

        // dot: registered weights x (regs for l=1, LDS stride-64 for l>1;
        // 2-way LDS alias is free)
        float acc = 0.f;
        if (l == 1) {
#pragma unroll
            for (int i = 0; i < 16; ++i)
                acc += wreg[0][i] * xreg[i];
        } else {
            const float* hr = h[(l - 1) & 1];
#pragma unroll
            for (int i = 0; i < 16; ++i)
                acc += wreg[(l - 1) & 1][i] * hr[lane + 64 * i];
        }
#pragma unroll
        for (int off = 32; off; off >>= 1)
            acc += __shfl_down(acc, off);

        if (lane == 0) {
            float pre = acc + bias[l - 1];
            if (l == NL_ - 1) out[row] = pre;                 // identity
            else {
                float v = pre / (1.f + __expf(-pre));         // silu
                st64(bufs[(l - 1) & 1] + row, pack(l, v));    // publish tag+data
            }
        }
    }
}

extern "C" void kernel_launch(void* const* d_in, const int* in_sizes, int n_in,
                              void* d_out, int out_size, void* d_ws, size_t ws_size,
                              hipStream_t stream) {
    const float* x      = (const float*)d_in[0];
    const float* params = (const float*)d_in[1];
    // d_in[2] = adj (bool): fixed layered-DAG structure, baked into indexing.
    float* out = (float*)d_out;
    float* ws  = (float*)d_ws;   // 16 KB used: 2 x 1024 packed u64 activations

    hipLaunchKernelGGL(mlp_fused, dim3(NBLK), dim3(256), 0, stream,
                       x, params, out, ws);
}